// Round 1
// baseline (61904.889 us; speedup 1.0000x reference)
//
#include <hip/hip_runtime.h>
#include <math.h>

#define B_ 32
#define T_ 512
#define D_ 1024
#define H_ 1024
#define L_ 4
#define KQ 256   // K range per k-quarter (one wave-group)
#define KT 32    // K tile staged in LDS per iteration
#define LROW 36  // padded LDS row stride (floats): 36*4B=144B, 16B-aligned, 2-way bank alias only

// Pipeline-skewed tick kernel: at tick, layer l computes timestep t = tick - l.
// All 4 layers are independent within a tick (deps are to the previous tick's
// kernel), so no intra-kernel cross-layer sync is needed.
// Grid: 256 blocks = 4 layers * 64 column-slices (16 cols each).
// Block: 512 threads = 4 j-quads * 32 rows * 4 K-quarters.
__global__ __launch_bounds__(512) void lnn_tick(
    const float* __restrict__ x,      // [B][T][D]
    const float* __restrict__ Hread,  // [L][B][H]  state at t-1
    float* __restrict__ Hwrite,       // [L][B][H]  state at t
    const float* __restrict__ W_in,   // [L][D][H]
    const float* __restrict__ b_in,   // [L][H]
    const float* __restrict__ W_h,    // [L][H][H]
    const float* __restrict__ b_h,    // [L][H]
    const float* __restrict__ tau,    // [L][H]
    int tick)
{
    const int bid   = blockIdx.x;
    const int layer = bid >> 6;
    const int t     = tick - layer;
    if (t < 0 || t >= T_) return;   // uniform per block

    const int jbase = (bid & 63) << 4;      // 16 output cols per block
    const int tid   = threadIdx.x;
    const int jq    = tid & 3;              // which j-quad (4 cols, float4)
    const int j     = jbase + (jq << 2);
    const int bk    = tid >> 2;             // 0..127
    const int b     = bk & 31;              // batch row
    const int kh    = bk >> 5;              // K-quarter 0..3

    __shared__ float  xs[4][32][LROW];      // staged layer input  [kq][b][kk]
    __shared__ float  hs[4][32][LROW];      // staged h(t-1)       [kq][b][kk]
    __shared__ float4 red[3][32][4];        // cross-quarter partials

    const float* Wl_in = W_in + (size_t)layer * D_ * H_;
    const float* Wl_h  = W_h  + (size_t)layer * H_ * H_;
    const float* hrow  = Hread + layer * (B_ * H_);

    const float* xsrc; int xstride;
    if (layer == 0) { xsrc = x + (size_t)t * D_;                   xstride = T_ * D_; }
    else            { xsrc = Hread + (layer - 1) * (B_ * H_);      xstride = H_;      }

    float4 acc = make_float4(0.f, 0.f, 0.f, 0.f);

    for (int kt = 0; kt < KQ; kt += KT) {
        __syncthreads();
        // Stage 4 quarters * 32 rows * KT floats of both x-input and h into LDS.
        // Per array: 4*32*8 = 1024 float4 -> 2 per thread.
        #pragma unroll
        for (int s = 0; s < 2; ++s) {
            const int fi  = (s << 9) + tid;  // 0..1023
            const int khs = fi >> 8;         // quarter
            const int r   = fi & 255;
            const int bs  = r >> 3;          // row
            const int kk  = (r & 7) << 2;    // float offset within tile
            const int kg  = khs * KQ + kt + kk;
            *(float4*)&xs[khs][bs][kk] = *(const float4*)&xsrc[(size_t)bs * xstride + kg];
            *(float4*)&hs[khs][bs][kk] = *(const float4*)&hrow[bs * H_ + kg];
        }
        __syncthreads();

        #pragma unroll
        for (int q = 0; q < KT / 4; ++q) {
            const int    kb  = kh * KQ + kt + (q << 2);
            const float4 xv  = *(const float4*)&xs[kh][b][q << 2];
            const float4 hv  = *(const float4*)&hs[kh][b][q << 2];
            const float* wip = Wl_in + (size_t)kb * H_ + j;
            const float* whp = Wl_h  + (size_t)kb * H_ + j;
            const float4 wi0 = *(const float4*)(wip);
            const float4 wi1 = *(const float4*)(wip +     H_);
            const float4 wi2 = *(const float4*)(wip + 2 * H_);
            const float4 wi3 = *(const float4*)(wip + 3 * H_);
            const float4 wh0 = *(const float4*)(whp);
            const float4 wh1 = *(const float4*)(whp +     H_);
            const float4 wh2 = *(const float4*)(whp + 2 * H_);
            const float4 wh3 = *(const float4*)(whp + 3 * H_);
            acc.x += xv.x*wi0.x + xv.y*wi1.x + xv.z*wi2.x + xv.w*wi3.x
                   + hv.x*wh0.x + hv.y*wh1.x + hv.z*wh2.x + hv.w*wh3.x;
            acc.y += xv.x*wi0.y + xv.y*wi1.y + xv.z*wi2.y + xv.w*wi3.y
                   + hv.x*wh0.y + hv.y*wh1.y + hv.z*wh2.y + hv.w*wh3.y;
            acc.z += xv.x*wi0.z + xv.y*wi1.z + xv.z*wi2.z + xv.w*wi3.z
                   + hv.x*wh0.z + hv.y*wh1.z + hv.z*wh2.z + hv.w*wh3.z;
            acc.w += xv.x*wi0.w + xv.y*wi1.w + xv.z*wi2.w + xv.w*wi3.w
                   + hv.x*wh0.w + hv.y*wh1.w + hv.z*wh2.w + hv.w*wh3.w;
        }
    }

    if (kh > 0) red[kh - 1][b][jq] = acc;
    __syncthreads();
    if (kh == 0) {
        float4 a = acc;
        #pragma unroll
        for (int qq = 0; qq < 3; ++qq) {
            const float4 o = red[qq][b][jq];
            a.x += o.x; a.y += o.y; a.z += o.z; a.w += o.w;
        }
        const float4 bi = *(const float4*)&b_in[layer * H_ + j];
        const float4 bh = *(const float4*)&b_h [layer * H_ + j];
        const float4 tv = *(const float4*)&tau [layer * H_ + j];
        const float4 ho = *(const float4*)&hrow[b * H_ + j];
        const float zx = tanhf(a.x + bi.x + bh.x);
        const float zy = tanhf(a.y + bi.y + bh.y);
        const float zz = tanhf(a.z + bi.z + bh.z);
        const float zw = tanhf(a.w + bi.w + bh.w);
        float4 hn;
        hn.x = ho.x + (zx - ho.x) / tv.x;
        hn.y = ho.y + (zy - ho.y) / tv.y;
        hn.z = ho.z + (zz - ho.z) / tv.z;
        hn.w = ho.w + (zw - ho.w) / tv.w;
        *(float4*)&Hwrite[layer * (B_ * H_) + b * H_ + j] = hn;
    }
}

// out[b][o] = sum_k h3[b][k] * W_out[k][o] + b_out[o]
__global__ __launch_bounds__(256) void lnn_out(
    const float* __restrict__ H3,     // [B][H]
    const float* __restrict__ W_out,  // [H][O]
    const float* __restrict__ b_out,  // [O]
    float* __restrict__ out)          // [B][O]
{
    const int gid = blockIdx.x * 256 + threadIdx.x;  // 64 blocks -> 16384 threads
    const int jj  = gid & 1023;
    const int b2  = gid >> 10;                       // 0..15 -> rows b2, b2+16
    float acc0 = b_out[jj];
    float acc1 = b_out[jj];
    for (int k = 0; k < H_; ++k) {
        const float w = W_out[k * H_ + jj];
        acc0 += H3[b2 * H_ + k]        * w;
        acc1 += H3[(b2 + 16) * H_ + k] * w;
    }
    out[b2 * H_ + jj]        = acc0;
    out[(b2 + 16) * H_ + jj] = acc1;
}

extern "C" void kernel_launch(void* const* d_in, const int* in_sizes, int n_in,
                              void* d_out, int out_size, void* d_ws, size_t ws_size,
                              hipStream_t stream) {
    const float* x     = (const float*)d_in[0];
    const float* W_in  = (const float*)d_in[1];
    const float* b_in  = (const float*)d_in[2];
    const float* W_h   = (const float*)d_in[3];
    const float* b_h   = (const float*)d_in[4];
    const float* tau   = (const float*)d_in[5];
    const float* W_out = (const float*)d_in[6];
    const float* b_out = (const float*)d_in[7];

    float* Hbuf = (float*)d_ws;                       // 2 * [L][B][H] state buffers
    const size_t stateElems = (size_t)L_ * B_ * H_;
    hipMemsetAsync(d_ws, 0, 2 * stateElems * sizeof(float), stream);

    const int nticks = T_ + L_ - 1;                   // 515
    for (int tick = 0; tick < nticks; ++tick) {
        float* Hr = Hbuf + ((tick + 1) & 1) * stateElems;
        float* Hw = Hbuf + (tick & 1) * stateElems;
        lnn_tick<<<256, 512, 0, stream>>>(x, Hr, Hw, W_in, b_in, W_h, b_h, tau, tick);
    }
    // h3 at t=511 was written at tick 514 into buffer (514 & 1) = 0
    const float* H3 = Hbuf + (((nticks - 1) & 1) * stateElems) + 3 * (B_ * H_);
    lnn_out<<<64, 256, 0, stream>>>(H3, W_out, b_out, (float*)d_out);
}